// Round 6
// baseline (739.781 us; speedup 1.0000x reference)
//
#include <hip/hip_runtime.h>
#include <hip/hip_bf16.h>

#define NUM_STEPS 10
#define DT 0.1f
#define SLOT_BYTES 49152

typedef __bf16 bf16_t;
typedef __bf16 bf16x8 __attribute__((ext_vector_type(8)));
typedef __bf16 bf16x4 __attribute__((ext_vector_type(4)));
typedef float f32x4 __attribute__((ext_vector_type(4)));

// async global->LDS, 16B per lane; LDS dst is wave-uniform base + lane*16
__device__ __forceinline__ void async16(const bf16_t* g, bf16_t* l) {
  __builtin_amdgcn_global_load_lds(
      (const __attribute__((address_space(1))) void*)g,
      (__attribute__((address_space(3))) void*)l, 16, 0, 0);
}

__global__ void cvt_f32_to_bf16(const float* __restrict__ in,
                                bf16_t* __restrict__ out, int n4) {
  int i = blockIdx.x * blockDim.x + threadIdx.x;
  if (i < n4) {
    float4 v = ((const float4*)in)[i];
    bf16x4 o = {(bf16_t)v.x, (bf16_t)v.y, (bf16_t)v.z, (bf16_t)v.w};
    ((bf16x4*)out)[i] = o;
  }
}

// one-shot: decay[h] = exp(-dt/tau[h])
__global__ void make_decay(const float* __restrict__ tau,
                           float* __restrict__ decay, int n) {
  int i = blockIdx.x * blockDim.x + threadIdx.x;
  if (i < n) decay[i] = __expf(-DT / tau[i]);
}

// C[M,N] = A[M,K] * B[N,K]^T   (NT, both row-major, K contiguous)
// Round 6 = round 5 resubmitted verbatim (round-5 bench was an infra
// failure: container died twice, no counters; deadlock audit of the vmcnt
// ledger / barrier uniformity / slot hazards found no kernel fault).
// Structure: m201 8-phase-style body at the verified geometry. BM=256 BN=128
// BK=64, 8 waves (4M x 2N, per-wave 64x64), frag-group LDS layout (0 bank
// conflicts, round-2-identical addresses). 3 slots x 48 KB, tile t in
// slot t%3. Per tile 2 phases (ks=0/1), each phase:
//   { 8 ds_read -> issue stage-unit for tile t+2 -> s_barrier ->
//     setprio(1) 16 MFMA setprio(0) -> s_barrier }
// Stage units: ph0 = A-halves of t+2 (4 gll), ph1 = B of t+2 (2 gll) ->
// every load has 4-8 phases (~1200-2400 cyc) of cover. vmcnt(6) ONCE per
// tile (before the final barrier); vmcnt(0) only at the NT-2 boundary.
// Rounds 2-4 (coarse phase-split, per-phase waits) all pinned at 71.7 us /
// ~10 B/cyc/CU; this is the m233/m196-isolated fix (read latency absorbed
// by barrier skew, MFMA cluster isolated between barriers).
// EPI=0: ihb(bf16) = acc + bias1[col] + bias2[col]
// EPI=1: pre = acc + ihb; hn = d*hb_prev + (1-d)*tanh(pre); hb_next = bf16(hn)
//        if writeOut: out_f32 = hn
template <int EPI>
__global__ __launch_bounds__(512, 2) void gemm_nt(
    const bf16_t* __restrict__ A, const bf16_t* __restrict__ Bw, int M, int N,
    int K, const float* __restrict__ bias1, const float* __restrict__ bias2,
    bf16_t* __restrict__ out_ihb, const bf16_t* __restrict__ ihb,
    const float* __restrict__ decay, const bf16_t* __restrict__ hb_prev,
    bf16_t* __restrict__ hb_next, float* __restrict__ out_f32, int writeOut) {
  extern __shared__ char smem[];  // 147456 B: 3 x 48 KB slots; 128 KB epi

  const int tid = threadIdx.x;
  const int lane = tid & 63;
  const int wave = tid >> 6;    // 0..7
  const int waveM = wave >> 1;  // 0..3  (64-row band of 256)
  const int waveN = wave & 1;   // 0..1  (64-col half of 128)

  // XCD swizzle (verified mapping; FETCH ~= compulsory)
  const int lin = blockIdx.y * gridDim.x + blockIdx.x;  // 0..255
  const int xcd = lin & 7;
  const int slot_ = lin >> 3;                    // 0..31
  const int bx = (xcd & 1) * 8 + (slot_ & 7);    // 0..15 (N/128)
  const int by = (xcd >> 1) * 4 + (slot_ >> 3);  // 0..15 (M/256)
  const long bRow = (long)by * 256;
  const long bCol = (long)bx * 128;

  // staging (8 waves, 6 gll/thread/tile in 2 units):
  //   unit A (ph0, 4 gll): wave w stages A-group w (rows w*16..) ks0/ks1 and
  //                        A-group 8+w (rows 128+w*16..) ks0/ks1
  //   unit B (ph1, 2 gll): wave w stages B-group w, ks0/ks1
  // lane -> row = lane&15, k = (lane>>4)*8 within a 32-wide k-slice
  // LDS frag layout per slot (elements): A group g at g*1024 + ks*512;
  // B group g at 16384 + g*1024 + ks*512. ds_read = lane*16B linear (0 conf).
  const int laneRow = lane & 15;
  const int laneK = (lane >> 4) << 3;
  const bf16_t* aGlo = A + (bRow + wave * 16 + laneRow) * (long)K + laneK;
  const bf16_t* aGhi = A + (bRow + 128 + wave * 16 + laneRow) * (long)K + laneK;
  const bf16_t* bG = Bw + (bCol + wave * 16 + laneRow) * (long)K + laneK;

  f32x4 acc[4][4] = {};

  auto stageA = [&](int slot, int k0) {  // 4 gll: A halves
    bf16_t* base = (bf16_t*)(smem + slot * SLOT_BYTES);
    async16(aGlo + k0, base + wave * 1024);
    async16(aGlo + k0 + 32, base + wave * 1024 + 512);
    async16(aGhi + k0, base + (8 + wave) * 1024);
    async16(aGhi + k0 + 32, base + (8 + wave) * 1024 + 512);
  };
  auto stageB = [&](int slot, int k0) {  // 2 gll: B
    bf16_t* base = (bf16_t*)(smem + slot * SLOT_BYTES);
    async16(bG + k0, base + 16384 + wave * 1024);
    async16(bG + k0 + 32, base + 16384 + wave * 1024 + 512);
  };

  const int NT = K >> 6;  // 16 or 32 K-tiles; tile t lives in slot t%3

  // prologue: tiles 0,1 fully staged (12 gll/thread outstanding)
  stageA(0, 0);
  stageB(0, 0);
  stageA(1, 64);
  stageB(1, 64);
  asm volatile("s_waitcnt vmcnt(6)" ::: "memory");  // tile 0 landed
  __builtin_amdgcn_s_barrier();
  __builtin_amdgcn_sched_barrier(0);

  for (int t = 0; t < NT; ++t) {
    const int slot = t % 3;
    const int ns = (t + 2) % 3;      // stage destination (readers done at t-1)
    const int k2 = (t + 2) * 64;
    const bool pf = (t + 2) < NT;
    const bf16_t* Ab = (const bf16_t*)(smem + slot * SLOT_BYTES);
    const bf16_t* Bb = Ab + 16384;

    // ---------------- phase 0 (ks = 0) ----------------
    {
      bf16x8 aF[4], bF[4];
#pragma unroll
      for (int i = 0; i < 4; ++i)
        aF[i] = *(const bf16x8*)&Ab[(waveM * 4 + i) * 1024 + lane * 8];
#pragma unroll
      for (int u = 0; u < 4; ++u)
        bF[u] = *(const bf16x8*)&Bb[(waveN * 4 + u) * 1024 + lane * 8];
      if (pf) stageA(ns, k2);  // unit A of tile t+2 (4 gll)
      __builtin_amdgcn_sched_barrier(0);
      __builtin_amdgcn_s_barrier();   // read latency absorbed by arrival skew
      __builtin_amdgcn_s_setprio(1);
#pragma unroll
      for (int i = 0; i < 4; ++i)
#pragma unroll
        for (int u = 0; u < 4; ++u)
          acc[i][u] = __builtin_amdgcn_mfma_f32_16x16x32_bf16(
              aF[i], bF[u], acc[i][u], 0, 0, 0);
      __builtin_amdgcn_s_setprio(0);
      __builtin_amdgcn_sched_barrier(0);
      __builtin_amdgcn_s_barrier();
    }
    // ---------------- phase 1 (ks = 1) ----------------
    {
      bf16x8 aF[4], bF[4];
#pragma unroll
      for (int i = 0; i < 4; ++i)
        aF[i] = *(const bf16x8*)&Ab[(waveM * 4 + i) * 1024 + 512 + lane * 8];
#pragma unroll
      for (int u = 0; u < 4; ++u)
        bF[u] = *(const bf16x8*)&Bb[(waveN * 4 + u) * 1024 + 512 + lane * 8];
      if (pf) stageB(ns, k2);  // unit B of tile t+2 (2 gll)
      __builtin_amdgcn_sched_barrier(0);
      __builtin_amdgcn_s_barrier();
      __builtin_amdgcn_s_setprio(1);
#pragma unroll
      for (int i = 0; i < 4; ++i)
#pragma unroll
        for (int u = 0; u < 4; ++u)
          acc[i][u] = __builtin_amdgcn_mfma_f32_16x16x32_bf16(
              aF[i], bF[u], acc[i][u], 0, 0, 0);
      __builtin_amdgcn_s_setprio(0);
      // counted wait ONCE per tile: ensure tile t+1 landed before next tile.
      // outstanding here = t+1's 6 (steady) + t+2's 6 just issued -> vmcnt(6).
      if (t < NT - 2) {
        asm volatile("s_waitcnt vmcnt(6)" ::: "memory");
      } else if (t == NT - 2) {
        asm volatile("s_waitcnt vmcnt(0)" ::: "memory");  // tail drain
      }
      __builtin_amdgcn_sched_barrier(0);
      __builtin_amdgcn_s_barrier();
    }
  }
  // loop exits after a barrier; all LDS reads consumed -> Ep reuse safe

  // ---- epilogue: LDS transpose (swizzled) then coalesced global I/O ----
  // C/D layout: col = lane&15, row = (lane>>4)*4 + reg   [measured m89/m91]
  float* Ep = (float*)smem;  // 256x128 f32 = 128 KB
  const int eRow = (lane >> 4) << 2;
  const int eCol = lane & 15;
#pragma unroll
  for (int i = 0; i < 4; ++i)
#pragma unroll
    for (int u = 0; u < 4; ++u)
#pragma unroll
      for (int r = 0; r < 4; ++r) {
        const int rowL = waveM * 64 + i * 16 + eRow + r;
        const int colL = waveN * 64 + u * 16 + eCol;
        // swizzle: phys = row*128 + ((col + 4*row) & 127)  (2-way max)
        Ep[rowL * 128 + ((colL + 4 * rowL) & 127)] = acc[i][u][r];
      }
  asm volatile("s_waitcnt lgkmcnt(0)" ::: "memory");
  __builtin_amdgcn_s_barrier();
  __builtin_amdgcn_sched_barrier(0);

  // readers: row = p*64 + tid>>3, 16 consecutive cols at (tid&7)*16
  const int rdRow = tid >> 3;
  const int col0 = (tid & 7) * 16;
#pragma unroll
  for (int p = 0; p < 4; ++p) {
    const int row = p * 64 + rdRow;
    float v[16];
#pragma unroll
    for (int c = 0; c < 4; ++c)
      *(f32x4*)&v[c * 4] =
          *(const f32x4*)&Ep[row * 128 + ((col0 + 4 * c + 4 * row) & 127)];
    const long g = (bRow + row) * (long)N + bCol + col0;

    if (EPI == 0) {
      f32x4 b1[4], b2[4];
#pragma unroll
      for (int c = 0; c < 4; ++c) {
        b1[c] = *(const f32x4*)&bias1[bCol + col0 + c * 4];
        b2[c] = *(const f32x4*)&bias2[bCol + col0 + c * 4];
      }
      bf16x8 o0, o1;
#pragma unroll
      for (int e = 0; e < 8; ++e)
        o0[e] = (bf16_t)(v[e] + b1[e >> 2][e & 3] + b2[e >> 2][e & 3]);
#pragma unroll
      for (int e = 0; e < 8; ++e)
        o1[e] = (bf16_t)(v[8 + e] + b1[2 + (e >> 2)][e & 3] +
                         b2[2 + (e >> 2)][e & 3]);
      *(bf16x8*)&out_ihb[g] = o0;  // 16B/lane, lanes consecutive
      *(bf16x8*)&out_ihb[g + 8] = o1;
    } else {
      const bf16x8 ih0 = *(const bf16x8*)&ihb[g];
      const bf16x8 ih1 = *(const bf16x8*)&ihb[g + 8];
      const bf16x8 hp0 = *(const bf16x8*)&hb_prev[g];
      const bf16x8 hp1 = *(const bf16x8*)&hb_prev[g + 8];
      f32x4 dc[4];
#pragma unroll
      for (int c = 0; c < 4; ++c)
        dc[c] = *(const f32x4*)&decay[bCol + col0 + c * 4];
      float hn[16];
      bf16x8 o0, o1;
#pragma unroll
      for (int e = 0; e < 8; ++e) {
        const float d = dc[e >> 2][e & 3];
        const float th = tanhf(v[e] + (float)ih0[e]);
        hn[e] = d * (float)hp0[e] + (1.0f - d) * th;
        o0[e] = (bf16_t)hn[e];
      }
#pragma unroll
      for (int e = 0; e < 8; ++e) {
        const float d = dc[2 + (e >> 2)][e & 3];
        const float th = tanhf(v[8 + e] + (float)ih1[e]);
        hn[8 + e] = d * (float)hp1[e] + (1.0f - d) * th;
        o1[e] = (bf16_t)hn[8 + e];
      }
      *(bf16x8*)&hb_next[g] = o0;
      *(bf16x8*)&hb_next[g + 8] = o1;
      if (writeOut) {
#pragma unroll
        for (int c = 0; c < 4; ++c)
          *(f32x4*)&out_f32[g + c * 4] = *(const f32x4*)&hn[c * 4];
      }
    }
  }
}

extern "C" void kernel_launch(void* const* d_in, const int* in_sizes, int n_in,
                              void* d_out, int out_size, void* d_ws,
                              size_t ws_size, hipStream_t stream) {
  const float* x = (const float*)d_in[0];
  const float* h0 = (const float*)d_in[1];
  const float* W_ih = (const float*)d_in[2];
  const float* b_ih = (const float*)d_in[3];
  const float* W_hh = (const float*)d_in[4];
  const float* b_hh = (const float*)d_in[5];
  const float* tau = (const float*)d_in[6];
  float* hout = (float*)d_out;

  const int B = 4096, I = 1024, H = 2048;

  char* ws = (char*)d_ws;
  bf16_t* ihb = (bf16_t*)ws; ws += (size_t)B * H * 2;   // 16 MB
  bf16_t* hb0 = (bf16_t*)ws; ws += (size_t)B * H * 2;   // 16 MB
  bf16_t* hb1 = (bf16_t*)ws; ws += (size_t)B * H * 2;   // 16 MB
  bf16_t* xb = (bf16_t*)ws;  ws += (size_t)B * I * 2;   // 8 MB
  bf16_t* wihb = (bf16_t*)ws; ws += (size_t)H * I * 2;  // 4 MB
  bf16_t* whhb = (bf16_t*)ws; ws += (size_t)H * H * 2;  // 8 MB
  float* decay = (float*)ws; ws += (size_t)H * 4;       // 8 KB

  const int LDS_BYTES = 147456;  // 3 x 48 KB slots; 128 KB epilogue reuse
  (void)hipFuncSetAttribute(reinterpret_cast<const void*>(&gemm_nt<0>),
                            hipFuncAttributeMaxDynamicSharedMemorySize,
                            LDS_BYTES);
  (void)hipFuncSetAttribute(reinterpret_cast<const void*>(&gemm_nt<1>),
                            hipFuncAttributeMaxDynamicSharedMemorySize,
                            LDS_BYTES);

  cvt_f32_to_bf16<<<(B * I / 4 + 255) / 256, 256, 0, stream>>>(x, xb, B * I / 4);
  cvt_f32_to_bf16<<<(H * I / 4 + 255) / 256, 256, 0, stream>>>(W_ih, wihb, H * I / 4);
  cvt_f32_to_bf16<<<(H * H / 4 + 255) / 256, 256, 0, stream>>>(W_hh, whhb, H * H / 4);
  cvt_f32_to_bf16<<<(B * H / 4 + 255) / 256, 256, 0, stream>>>(h0, hb0, B * H / 4);
  make_decay<<<(H + 255) / 256, 256, 0, stream>>>(tau, decay, H);

  dim3 grid(H / 128, B / 256);  // (16, 16) = 256 blocks = 1/CU
  // ihb = x @ W_ih^T + b_ih + b_hh   (fold both biases once, store bf16)
  gemm_nt<0><<<grid, 512, LDS_BYTES, stream>>>(
      xb, wihb, B, H, I, b_ih, b_hh, ihb, nullptr, nullptr, nullptr, nullptr,
      nullptr, 0);

  bf16_t* hb[2] = {hb0, hb1};
  for (int s = 0; s < NUM_STEPS; ++s) {
    gemm_nt<1><<<grid, 512, LDS_BYTES, stream>>>(
        hb[s & 1], whhb, B, H, H, nullptr, nullptr, nullptr, ihb, decay,
        hb[s & 1], hb[(s + 1) & 1], hout, (s == NUM_STEPS - 1) ? 1 : 0);
  }
}